// Round 3
// baseline (192718.835 us; speedup 1.0000x reference)
//
#include <hip/hip_runtime.h>
#include <cstdint>
#include <cstddef>

#define Bsz 64
#define Ssz 2048
#define Isz 256
#define Hsz 512

// ============================================================================
// Kernel 1: xproj GEMM  (unchanged — ~0.3 ms)
//   out[m][n] = sum_k x[m][k] * Wih[n][k] + bih[n] + bhh[n]
// ============================================================================
__global__ __launch_bounds__(256) void xproj_gemm(
    const float* __restrict__ x, const float* __restrict__ Wih,
    const float* __restrict__ bih, const float* __restrict__ bhh,
    float* __restrict__ out)
{
    __shared__ float As[64][136];
    __shared__ float Bs[64][136];

    const int tid = threadIdx.x;
    const int tx = tid & 15;
    const int ty = tid >> 4;
    const int m_blk = blockIdx.y * 128;
    const int n_blk = blockIdx.x * 128;

    float acc[8][8];
#pragma unroll
    for (int i = 0; i < 8; ++i)
#pragma unroll
        for (int j = 0; j < 8; ++j) acc[i][j] = 0.f;

    const int srow = tid >> 1;
    const int skh  = (tid & 1) * 32;

    for (int kt = 0; kt < Isz; kt += 64) {
        const float* ga = x   + (size_t)(m_blk + srow) * Isz + kt + skh;
        const float* gb = Wih + (size_t)(n_blk + srow) * Isz + kt + skh;
#pragma unroll
        for (int q = 0; q < 8; ++q) {
            const float4 va = *(const float4*)(ga + q * 4);
            As[skh + q * 4 + 0][srow] = va.x;
            As[skh + q * 4 + 1][srow] = va.y;
            As[skh + q * 4 + 2][srow] = va.z;
            As[skh + q * 4 + 3][srow] = va.w;
            const float4 vb = *(const float4*)(gb + q * 4);
            Bs[skh + q * 4 + 0][srow] = vb.x;
            Bs[skh + q * 4 + 1][srow] = vb.y;
            Bs[skh + q * 4 + 2][srow] = vb.z;
            Bs[skh + q * 4 + 3][srow] = vb.w;
        }
        __syncthreads();

#pragma unroll 4
        for (int k = 0; k < 64; ++k) {
            const float4 a0 = *(const float4*)&As[k][ty * 8];
            const float4 a1 = *(const float4*)&As[k][ty * 8 + 4];
            const float4 b0 = *(const float4*)&Bs[k][tx * 8];
            const float4 b1 = *(const float4*)&Bs[k][tx * 8 + 4];
            const float av[8] = {a0.x, a0.y, a0.z, a0.w, a1.x, a1.y, a1.z, a1.w};
            const float bv[8] = {b0.x, b0.y, b0.z, b0.w, b1.x, b1.y, b1.z, b1.w};
#pragma unroll
            for (int i = 0; i < 8; ++i)
#pragma unroll
                for (int j = 0; j < 8; ++j)
                    acc[i][j] = fmaf(av[i], bv[j], acc[i][j]);
        }
        __syncthreads();
    }

    const int m0 = m_blk + ty * 8;
    const int n0 = n_blk + tx * 8;
    float bias[8];
#pragma unroll
    for (int j = 0; j < 8; ++j) bias[j] = bih[n0 + j] + bhh[n0 + j];
#pragma unroll
    for (int i = 0; i < 8; ++i) {
        const float4 o0 = make_float4(acc[i][0] + bias[0], acc[i][1] + bias[1],
                                      acc[i][2] + bias[2], acc[i][3] + bias[3]);
        const float4 o1 = make_float4(acc[i][4] + bias[4], acc[i][5] + bias[5],
                                      acc[i][6] + bias[6], acc[i][7] + bias[7]);
        *(float4*)(out + (size_t)(m0 + i) * Hsz + n0)     = o0;
        *(float4*)(out + (size_t)(m0 + i) * Hsz + n0 + 4) = o1;
    }
}

// ============================================================================
// Kernel 2: model-parallel recurrent scan.
//   4 blocks per batch element (grid = 256 = #CUs, each block forced to its
//   own CU by 96 KB dynamic-LDS). Block (g,q) owns output rows
//   [q*128, q*128+128) of batch g. W slice is fully register-resident:
//   64 floats/thread (wave w = k-chunk [32w,32w+32); lane l = local rows
//   l and l+64). Per-step cross-block h exchange through parity-2 buffers
//   in d_ws with device-scope release/acquire flags. Max skew between
//   sibling blocks is 1 step -> 2 parity buffers suffice.
//   blockIdx mapping co-locates a batch's 4 blocks on one XCD (heuristic;
//   correctness relies only on agent-scope atomics).
// ============================================================================
__device__ __forceinline__ float bcast_lane(float v, int lane) {
    return __builtin_bit_cast(float,
        __builtin_amdgcn_readlane(__builtin_bit_cast(int, v), lane));
}

__global__ __launch_bounds__(1024, 4) void rnn_scan4(
    const float* __restrict__ Whh, float* __restrict__ out,
    unsigned int* __restrict__ flags, float* __restrict__ hbuf)
{
    __shared__ float pt[16][128];   // per-k-chunk partials (8 KB)
    __shared__ float h_own[128];    // this block's slice of h_t
    extern __shared__ char dyn_pad[];   // 96 KB requested -> 1 block/CU
    (void)dyn_pad;

    const int bi   = blockIdx.x;
    const int xcd  = bi & 7;
    const int slot = bi >> 3;
    const int g    = xcd * 8 + (slot >> 2);  // batch 0..63
    const int q    = slot & 3;               // quarter 0..3
    const int tid  = threadIdx.x;
    const int w    = tid >> 6;               // wave 0..15 -> k-chunk
    const int l    = tid & 63;
    const int l31  = l & 31;
    const int kb   = w * 32;                 // global k base of this wave

    // ---- register-resident weight slice: rows q*128 + {l, 64+l}, k-chunk kb ----
    float wreg[2][32];
#pragma unroll
    for (int i = 0; i < 2; ++i) {
        const float* wp = Whh + (size_t)(q * 128 + i * 64 + l) * Hsz + kb;
#pragma unroll
        for (int v4 = 0; v4 < 8; ++v4) {
            const float4 v = *(const float4*)(wp + 4 * v4);
            wreg[i][4 * v4 + 0] = v.x;
            wreg[i][4 * v4 + 1] = v.y;
            wreg[i][4 * v4 + 2] = v.z;
            wreg[i][4 * v4 + 3] = v.w;
        }
    }

    unsigned int* fl = flags + g * 4;
    float* outg = out + (size_t)g * Ssz * Hsz;

    float hv = 0.f;   // lane l31 holds h_{t-1}[kb + l31]; h_{-1} = 0

    for (int t = 0; t < Ssz; ++t) {
        // xproj for this block's slice — issue early, hides under FMA phase
        float xp = 0.f;
        if (tid < 128) xp = outg[(size_t)t * Hsz + q * 128 + tid];

        // ---- FMA phase: 32 readlane broadcasts, 64 FMAs ----
        float acc0 = 0.f, acc1 = 0.f;
#pragma unroll
        for (int kk = 0; kk < 32; ++kk) {
            const float s = bcast_lane(hv, kk);   // h_{t-1}[kb+kk] as SGPR
            acc0 = fmaf(wreg[0][kk], s, acc0);
            acc1 = fmaf(wreg[1][kk], s, acc1);
        }
        pt[w][l]      = acc0;
        pt[w][64 + l] = acc1;
        __syncthreads();

        // ---- reduce + tanh + publish (waves 0,1) ----
        if (tid < 128) {
            float sum = xp;
#pragma unroll
            for (int c = 0; c < 16; ++c) sum += pt[c][tid];
            const float hn = tanhf(sum);
            outg[(size_t)t * Hsz + q * 128 + tid] = hn;   // final output
            h_own[tid] = hn;                               // local reuse
            __hip_atomic_store(
                &hbuf[((size_t)(t & 1) * Bsz + g) * Hsz + q * 128 + tid], hn,
                __ATOMIC_RELAXED, __HIP_MEMORY_SCOPE_AGENT);
        }
        __threadfence();        // make hbuf stores agent-visible
        __syncthreads();

        if (t < Ssz - 1) {
            if (tid == 0)
                __hip_atomic_store(&fl[q], (unsigned)(t + 1),
                                   __ATOMIC_RELEASE, __HIP_MEMORY_SCOPE_AGENT);
            // ---- gather h_t chunk for next step ----
            const int qn = w >> 2;      // quarter owning this wave's k-chunk
            if (qn == q) {
                hv = h_own[(w & 3) * 32 + l31];
            } else {
                while (__hip_atomic_load(&fl[qn], __ATOMIC_ACQUIRE,
                                         __HIP_MEMORY_SCOPE_AGENT)
                       < (unsigned)(t + 1)) {}
                hv = __hip_atomic_load(
                    &hbuf[((size_t)(t & 1) * Bsz + g) * Hsz + kb + l31],
                    __ATOMIC_RELAXED, __HIP_MEMORY_SCOPE_AGENT);
            }
        }
    }
}

// ============================================================================
extern "C" void kernel_launch(void* const* d_in, const int* in_sizes, int n_in,
                              void* d_out, int out_size, void* d_ws, size_t ws_size,
                              hipStream_t stream)
{
    const float* x   = (const float*)d_in[0];   // (B,S,I)
    const float* Wih = (const float*)d_in[1];   // (H,I)
    const float* Whh = (const float*)d_in[2];   // (H,H)
    const float* bih = (const float*)d_in[3];   // (H)
    const float* bhh = (const float*)d_in[4];   // (H)
    float* out = (float*)d_out;                 // (B,S,H)

    // d_ws layout: [flags: 64*4 u32 = 1 KB][hbuf: 2*64*512 f32 = 256 KB]
    unsigned int* flags = (unsigned int*)d_ws;
    float* hbuf = (float*)((char*)d_ws + 1024);
    hipMemsetAsync(d_ws, 0, 1024, stream);      // reset flags each launch

    dim3 g1(Hsz / 128, (Bsz * Ssz) / 128);      // (4, 1024)
    xproj_gemm<<<g1, 256, 0, stream>>>(x, Wih, bih, bhh, out);

    rnn_scan4<<<256, 1024, 96 * 1024, stream>>>(Whh, out, flags, hbuf);
}

// Round 4
// 7988.132 us; speedup vs baseline: 24.1256x; 24.1256x over previous
//
#include <hip/hip_runtime.h>
#include <cstdint>
#include <cstddef>

#define Bsz 64
#define Ssz 2048
#define Isz 256
#define Hsz 512

typedef _Float16 v2h __attribute__((ext_vector_type(2)));

// ============================================================================
// Kernel 0: convert W_hh (fp32, HxH) -> packed f16 pairs in d_ws.
//   w16u[row*256 + j] = half2(W[row][2j], W[row][2j+1])
// ============================================================================
__global__ __launch_bounds__(256) void convert_w16(
    const float* __restrict__ Whh, uint32_t* __restrict__ w16u)
{
    const int idx = (blockIdx.x * 256 + threadIdx.x) * 4;   // 4 floats
    const float4 v = *(const float4*)(Whh + idx);
    const v2h a = { (_Float16)v.x, (_Float16)v.y };
    const v2h b = { (_Float16)v.z, (_Float16)v.w };
    w16u[(idx >> 1) + 0] = __builtin_bit_cast(uint32_t, a);
    w16u[(idx >> 1) + 1] = __builtin_bit_cast(uint32_t, b);
}

// ============================================================================
// Kernel 1: xproj GEMM (unchanged, ~0.3 ms)
//   out[m][n] = sum_k x[m][k] * Wih[n][k] + bih[n] + bhh[n]
// ============================================================================
__global__ __launch_bounds__(256) void xproj_gemm(
    const float* __restrict__ x, const float* __restrict__ Wih,
    const float* __restrict__ bih, const float* __restrict__ bhh,
    float* __restrict__ out)
{
    __shared__ float As[64][136];
    __shared__ float Bs[64][136];

    const int tid = threadIdx.x;
    const int tx = tid & 15;
    const int ty = tid >> 4;
    const int m_blk = blockIdx.y * 128;
    const int n_blk = blockIdx.x * 128;

    float acc[8][8];
#pragma unroll
    for (int i = 0; i < 8; ++i)
#pragma unroll
        for (int j = 0; j < 8; ++j) acc[i][j] = 0.f;

    const int srow = tid >> 1;
    const int skh  = (tid & 1) * 32;

    for (int kt = 0; kt < Isz; kt += 64) {
        const float* ga = x   + (size_t)(m_blk + srow) * Isz + kt + skh;
        const float* gb = Wih + (size_t)(n_blk + srow) * Isz + kt + skh;
#pragma unroll
        for (int q = 0; q < 8; ++q) {
            const float4 va = *(const float4*)(ga + q * 4);
            As[skh + q * 4 + 0][srow] = va.x;
            As[skh + q * 4 + 1][srow] = va.y;
            As[skh + q * 4 + 2][srow] = va.z;
            As[skh + q * 4 + 3][srow] = va.w;
            const float4 vb = *(const float4*)(gb + q * 4);
            Bs[skh + q * 4 + 0][srow] = vb.x;
            Bs[skh + q * 4 + 1][srow] = vb.y;
            Bs[skh + q * 4 + 2][srow] = vb.z;
            Bs[skh + q * 4 + 3][srow] = vb.w;
        }
        __syncthreads();

#pragma unroll 4
        for (int k = 0; k < 64; ++k) {
            const float4 a0 = *(const float4*)&As[k][ty * 8];
            const float4 a1 = *(const float4*)&As[k][ty * 8 + 4];
            const float4 b0 = *(const float4*)&Bs[k][tx * 8];
            const float4 b1 = *(const float4*)&Bs[k][tx * 8 + 4];
            const float av[8] = {a0.x, a0.y, a0.z, a0.w, a1.x, a1.y, a1.z, a1.w};
            const float bv[8] = {b0.x, b0.y, b0.z, b0.w, b1.x, b1.y, b1.z, b1.w};
#pragma unroll
            for (int i = 0; i < 8; ++i)
#pragma unroll
                for (int j = 0; j < 8; ++j)
                    acc[i][j] = fmaf(av[i], bv[j], acc[i][j]);
        }
        __syncthreads();
    }

    const int m0 = m_blk + ty * 8;
    const int n0 = n_blk + tx * 8;
    float bias[8];
#pragma unroll
    for (int j = 0; j < 8; ++j) bias[j] = bih[n0 + j] + bhh[n0 + j];
#pragma unroll
    for (int i = 0; i < 8; ++i) {
        const float4 o0 = make_float4(acc[i][0] + bias[0], acc[i][1] + bias[1],
                                      acc[i][2] + bias[2], acc[i][3] + bias[3]);
        const float4 o1 = make_float4(acc[i][4] + bias[4], acc[i][5] + bias[5],
                                      acc[i][6] + bias[6], acc[i][7] + bias[7]);
        *(float4*)(out + (size_t)(m0 + i) * Hsz + n0)     = o0;
        *(float4*)(out + (size_t)(m0 + i) * Hsz + n0 + 4) = o1;
    }
}

// ============================================================================
// Kernel 2: recurrent scan — 1 block/batch, 512 threads (8 waves, 2/SIMD,
// VGPR cap 256). W_hh resident as f16 on the CU:
//   wave w owns k-pairs [32w, 32w+32); lane l owns rows 64i+l, i=0..7.
//   i=0..5  -> RF  (192 VGPRs of packed f16x2 per thread)
//   i=6,7   -> LDS (128 KB), XOR-swizzled: word (row,j) at [row*256 + (j^row&31)]
// h_{t-1} broadcast: lane loads one packed f16-pair word from LDS, then 32
// compile-time readlane -> SGPR operand of v_dot2_f32_f16 (fp32 accumulate).
// Cross-wave k-reduction via pt[8][512] LDS, tanh in fp32, h stored to LDS
// as f16 for the next step, full-precision fp32 to out.
// ============================================================================
__global__ __launch_bounds__(512, 2) void rnn_scan_f16(
    const uint32_t* __restrict__ w16u,   // [512 rows][256 pairs]
    float* __restrict__ out)
{
    extern __shared__ uint8_t dyn[];
    uint32_t* lds_w = (uint32_t*)dyn;                      // [128][256] 128 KB
    float*    pt    = (float*)(dyn + 131072);              // [8][512]    16 KB
    uint32_t* h16   = (uint32_t*)(dyn + 131072 + 16384);   // 256 words    1 KB

    const int b   = blockIdx.x;
    const int tid = threadIdx.x;
    const int w   = tid >> 6;
    const int l   = tid & 63;
    const int kp  = w * 32;          // pair base of this wave's k-chunk
    const int s5  = l & 31;          // swizzle key

    // ---- RF rows i=0..5 (rows 64i+l), one-time load ----
    uint32_t wr[6][32];
#pragma unroll
    for (int i = 0; i < 6; ++i) {
        const uint32_t* src = w16u + (i * 64 + l) * 256 + kp;
#pragma unroll
        for (int q = 0; q < 8; ++q) {
            const uint4 v = *(const uint4*)(src + 4 * q);
            wr[i][4 * q + 0] = v.x;
            wr[i][4 * q + 1] = v.y;
            wr[i][4 * q + 2] = v.z;
            wr[i][4 * q + 3] = v.w;
        }
    }

    // ---- LDS rows 384..511 (lds row lr = row-384), XOR-swizzled ----
    {
        const int lr = tid >> 2;            // 0..127
        const int qt = tid & 3;
        const uint32_t* src = w16u + (384 + lr) * 256 + qt * 64;
#pragma unroll
        for (int jj = 0; jj < 64; ++jj)
            lds_w[lr * 256 + ((qt * 64 + jj) ^ (lr & 31))] = src[jj];
    }
    if (tid < 256) h16[tid] = 0u;           // h_{-1} = 0
    __syncthreads();

    float* outg = out + (size_t)b * Ssz * Hsz;
    const int lw0 = l * 256;                // lds row of global row 384+l
    const int lw1 = (64 + l) * 256;         // lds row of global row 448+l

    for (int t = 0; t < Ssz; ++t) {
        const float    xp  = outg[(size_t)t * Hsz + tid];  // xproj (early issue)
        const uint32_t hpu = h16[kp + s5];  // lane s5 holds h-pair kp+s5

        float acc[8];
#pragma unroll
        for (int i = 0; i < 8; ++i) acc[i] = 0.f;

        uint32_t c0 = lds_w[lw0 + ((kp + 0) ^ s5)];
        uint32_t c1 = lds_w[lw1 + ((kp + 0) ^ s5)];
#pragma unroll
        for (int p = 0; p < 32; ++p) {
            uint32_t n0 = 0, n1 = 0;
            if (p < 31) {                   // static ring, prefetch distance 1
                n0 = lds_w[lw0 + ((kp + p + 1) ^ s5)];
                n1 = lds_w[lw1 + ((kp + p + 1) ^ s5)];
            }
            const v2h hb = __builtin_bit_cast(v2h,
                __builtin_amdgcn_readlane(__builtin_bit_cast(int, hpu), p));
#pragma unroll
            for (int i = 0; i < 6; ++i)
                acc[i] = __builtin_amdgcn_fdot2(
                    __builtin_bit_cast(v2h, wr[i][p]), hb, acc[i], false);
            acc[6] = __builtin_amdgcn_fdot2(
                __builtin_bit_cast(v2h, c0), hb, acc[6], false);
            acc[7] = __builtin_amdgcn_fdot2(
                __builtin_bit_cast(v2h, c1), hb, acc[7], false);
            c0 = n0; c1 = n1;
        }

#pragma unroll
        for (int i = 0; i < 8; ++i) pt[w * 512 + i * 64 + l] = acc[i];
        __syncthreads();

        // reduce over the 8 k-chunks + tanh; thread tid owns output row tid
        float sum = xp;
#pragma unroll
        for (int c = 0; c < 8; ++c) sum += pt[c * 512 + tid];
        const float ax = fabsf(sum);
        const float u  = __expf(-2.f * ax);
        float th = (1.f - u) * __builtin_amdgcn_rcpf(1.f + u);
        th = copysignf(th, sum);

        outg[(size_t)t * Hsz + tid] = th;                    // fp32 output
        ((uint16_t*)h16)[tid] =
            __builtin_bit_cast(uint16_t, (_Float16)th);      // f16 h for t+1
        __syncthreads();
    }
}

// ============================================================================
extern "C" void kernel_launch(void* const* d_in, const int* in_sizes, int n_in,
                              void* d_out, int out_size, void* d_ws, size_t ws_size,
                              hipStream_t stream)
{
    const float* x   = (const float*)d_in[0];   // (B,S,I)
    const float* Wih = (const float*)d_in[1];   // (H,I)
    const float* Whh = (const float*)d_in[2];   // (H,H)
    const float* bih = (const float*)d_in[3];   // (H)
    const float* bhh = (const float*)d_in[4];   // (H)
    float* out = (float*)d_out;                 // (B,S,H)

    uint32_t* w16u = (uint32_t*)d_ws;           // 512 KB packed f16 W_hh

    convert_w16<<<256, 256, 0, stream>>>(Whh, w16u);

    dim3 g1(Hsz / 128, (Bsz * Ssz) / 128);      // (4, 1024)
    xproj_gemm<<<g1, 256, 0, stream>>>(x, Wih, bih, bhh, out);

    // 131072 (lds_w) + 16384 (pt) + 1024 (h16) = 148480 B dynamic LDS
    rnn_scan_f16<<<Bsz, 512, 148480, stream>>>(w16u, out);
}

// Round 5
// 3684.719 us; speedup vs baseline: 52.3022x; 2.1679x over previous
//
#include <hip/hip_runtime.h>
#include <cstdint>
#include <cstddef>

#define Bsz 64
#define Ssz 2048
#define Isz 256
#define Hsz 512

typedef _Float16 v2h __attribute__((ext_vector_type(2)));

// ============================================================================
// Kernel 0: convert W_hh (fp32, HxH) -> packed f16 pairs in d_ws.
// ============================================================================
__global__ __launch_bounds__(256) void convert_w16(
    const float* __restrict__ Whh, uint32_t* __restrict__ w16u)
{
    const int idx = (blockIdx.x * 256 + threadIdx.x) * 4;
    const float4 v = *(const float4*)(Whh + idx);
    const v2h a = { (_Float16)v.x, (_Float16)v.y };
    const v2h b = { (_Float16)v.z, (_Float16)v.w };
    w16u[(idx >> 1) + 0] = __builtin_bit_cast(uint32_t, a);
    w16u[(idx >> 1) + 1] = __builtin_bit_cast(uint32_t, b);
}

// ============================================================================
// Kernel 1: xproj GEMM (unchanged, ~0.35 ms)
// ============================================================================
__global__ __launch_bounds__(256) void xproj_gemm(
    const float* __restrict__ x, const float* __restrict__ Wih,
    const float* __restrict__ bih, const float* __restrict__ bhh,
    float* __restrict__ out)
{
    __shared__ float As[64][136];
    __shared__ float Bs[64][136];

    const int tid = threadIdx.x;
    const int tx = tid & 15;
    const int ty = tid >> 4;
    const int m_blk = blockIdx.y * 128;
    const int n_blk = blockIdx.x * 128;

    float acc[8][8];
#pragma unroll
    for (int i = 0; i < 8; ++i)
#pragma unroll
        for (int j = 0; j < 8; ++j) acc[i][j] = 0.f;

    const int srow = tid >> 1;
    const int skh  = (tid & 1) * 32;

    for (int kt = 0; kt < Isz; kt += 64) {
        const float* ga = x   + (size_t)(m_blk + srow) * Isz + kt + skh;
        const float* gb = Wih + (size_t)(n_blk + srow) * Isz + kt + skh;
#pragma unroll
        for (int q = 0; q < 8; ++q) {
            const float4 va = *(const float4*)(ga + q * 4);
            As[skh + q * 4 + 0][srow] = va.x;
            As[skh + q * 4 + 1][srow] = va.y;
            As[skh + q * 4 + 2][srow] = va.z;
            As[skh + q * 4 + 3][srow] = va.w;
            const float4 vb = *(const float4*)(gb + q * 4);
            Bs[skh + q * 4 + 0][srow] = vb.x;
            Bs[skh + q * 4 + 1][srow] = vb.y;
            Bs[skh + q * 4 + 2][srow] = vb.z;
            Bs[skh + q * 4 + 3][srow] = vb.w;
        }
        __syncthreads();

#pragma unroll 4
        for (int k = 0; k < 64; ++k) {
            const float4 a0 = *(const float4*)&As[k][ty * 8];
            const float4 a1 = *(const float4*)&As[k][ty * 8 + 4];
            const float4 b0 = *(const float4*)&Bs[k][tx * 8];
            const float4 b1 = *(const float4*)&Bs[k][tx * 8 + 4];
            const float av[8] = {a0.x, a0.y, a0.z, a0.w, a1.x, a1.y, a1.z, a1.w};
            const float bv[8] = {b0.x, b0.y, b0.z, b0.w, b1.x, b1.y, b1.z, b1.w};
#pragma unroll
            for (int i = 0; i < 8; ++i)
#pragma unroll
                for (int j = 0; j < 8; ++j)
                    acc[i][j] = fmaf(av[i], bv[j], acc[i][j]);
        }
        __syncthreads();
    }

    const int m0 = m_blk + ty * 8;
    const int n0 = n_blk + tx * 8;
    float bias[8];
#pragma unroll
    for (int j = 0; j < 8; ++j) bias[j] = bih[n0 + j] + bhh[n0 + j];
#pragma unroll
    for (int i = 0; i < 8; ++i) {
        const float4 o0 = make_float4(acc[i][0] + bias[0], acc[i][1] + bias[1],
                                      acc[i][2] + bias[2], acc[i][3] + bias[3]);
        const float4 o1 = make_float4(acc[i][4] + bias[4], acc[i][5] + bias[5],
                                      acc[i][6] + bias[6], acc[i][7] + bias[7]);
        *(float4*)(out + (size_t)(m0 + i) * Hsz + n0)     = o0;
        *(float4*)(out + (size_t)(m0 + i) * Hsz + n0 + 4) = o1;
    }
}

// ============================================================================
// Kernel 2: recurrent scan — 1 block/batch, 512 threads, 2 waves/SIMD.
//   Wave w: k-pairs [32w, 32w+32). Lane l: rows 64i+l, i=0..7.
//   i=0..5 in RF (192 packed-f16x2 words); i=6,7 in LDS (128 KB),
//   16B-block XOR swizzle -> conflict-free ds_read_b128, ring-3 prefetch.
//   Per step: ONE barrier. Partials as f16 pairs in parity-2 LDS buffer;
//   each thread reduces its own h-pair (rows 2(kp+s5),+1) redundantly and
//   keeps it in a register -> next step's readlane needs no LDS, no barrier.
//   xproj prefetched one step ahead (float2/thread).
// ============================================================================
__global__ __launch_bounds__(512, 2) __attribute__((amdgpu_waves_per_eu(2, 2)))
void rnn_scan_f16(const uint32_t* __restrict__ w16u, float* __restrict__ out)
{
    extern __shared__ uint32_t dynw[];
    uint32_t* lds_w = dynw;            // [128 rows][256 words] 128 KB (swizzled)
    uint32_t* ptH   = dynw + 32768;    // 2 parities x [8 chunks][256 pairs] 16 KB

    const int tid = threadIdx.x;
    const int w   = tid >> 6;          // wave -> k-pair chunk
    const int l   = tid & 63;
    const int s5  = l & 31;
    const int kp  = w << 5;            // pair base
    const int key = l & 7;             // b128-block swizzle key
    const int w8  = w << 3;            // block base of this wave's k-chunk

    // ---- RF rows i=0..5 (rows 64i+l) ----
    uint32_t wr[6][32];
#pragma unroll
    for (int i = 0; i < 6; ++i) {
        const uint32_t* src = w16u + (i * 64 + l) * 256 + kp;
#pragma unroll
        for (int q = 0; q < 8; ++q) {
            const uint4 v = *(const uint4*)(src + 4 * q);
            wr[i][4 * q + 0] = v.x;
            wr[i][4 * q + 1] = v.y;
            wr[i][4 * q + 2] = v.z;
            wr[i][4 * q + 3] = v.w;
        }
    }

    // ---- stage rows 384..511 into LDS, 16B-block XOR swizzle ----
    {
        const int lr = tid >> 2;                 // local row 0..127
        const int qt = tid & 3;
        const uint32_t* src = w16u + (384 + lr) * 256 + qt * 64;
        uint32_t* dst = lds_w + lr * 256;
#pragma unroll
        for (int b = 0; b < 16; ++b) {
            const int blk = qt * 16 + b;         // 4-word block index 0..63
            const uint4 v = *(const uint4*)(src + b * 4);
            *(uint4*)(dst + (((blk ^ (lr & 7)) << 2))) = v;
        }
    }
    __syncthreads();

    float* outg = out + (size_t)blockIdx.x * (size_t)Ssz * Hsz;
    const int colbase = 2 * (kp + s5);           // this thread's h/out columns
    uint32_t* wrow6 = lds_w + l * 256;           // local row l   (global 384+l)
    uint32_t* wrow7 = lds_w + (64 + l) * 256;    // local row 64+l (global 448+l)

    uint32_t hp = 0;                                       // h pair f16x2
    float2 xp2 = *(const float2*)(outg + colbase);         // xproj row 0

    for (int t = 0; t < Ssz; ++t) {
        // prefetch next step's xproj (consumed after next barrier)
        const size_t nrow = (size_t)(t + 1 < Ssz ? t + 1 : t) * Hsz;
        const float2 xpn = *(const float2*)(outg + nrow + colbase);

        float acc[8];
#pragma unroll
        for (int i = 0; i < 8; ++i) acc[i] = 0.f;

        // ring-3 b128 prefetch of the two LDS-resident rows
        uint4 r6[3], r7[3];
        r6[0] = *(const uint4*)(wrow6 + (((w8 + 0) ^ key) << 2));
        r7[0] = *(const uint4*)(wrow7 + (((w8 + 0) ^ key) << 2));
        r6[1] = *(const uint4*)(wrow6 + (((w8 + 1) ^ key) << 2));
        r7[1] = *(const uint4*)(wrow7 + (((w8 + 1) ^ key) << 2));

#pragma unroll
        for (int g = 0; g < 8; ++g) {
            if (g < 6) {
                r6[(g + 2) % 3] = *(const uint4*)(wrow6 + (((w8 + g + 2) ^ key) << 2));
                r7[(g + 2) % 3] = *(const uint4*)(wrow7 + (((w8 + g + 2) ^ key) << 2));
            }
            const uint32_t c6[4] = {r6[g % 3].x, r6[g % 3].y, r6[g % 3].z, r6[g % 3].w};
            const uint32_t c7[4] = {r7[g % 3].x, r7[g % 3].y, r7[g % 3].z, r7[g % 3].w};
#pragma unroll
            for (int j = 0; j < 4; ++j) {
                const int p = g * 4 + j;
                const v2h hb = __builtin_bit_cast(v2h,
                    __builtin_amdgcn_readlane(__builtin_bit_cast(int, hp), p));
#pragma unroll
                for (int i = 0; i < 6; ++i)
                    acc[i] = __builtin_amdgcn_fdot2(
                        __builtin_bit_cast(v2h, wr[i][p]), hb, acc[i], false);
                acc[6] = __builtin_amdgcn_fdot2(
                    __builtin_bit_cast(v2h, c6[j]), hb, acc[6], false);
                acc[7] = __builtin_amdgcn_fdot2(
                    __builtin_bit_cast(v2h, c7[j]), hb, acc[7], false);
            }
        }

        // ---- publish partials as f16 (parity buffer t&1) ----
        uint16_t* ph = (uint16_t*)(ptH + (t & 1) * 2048);
#pragma unroll
        for (int i = 0; i < 8; ++i)
            ph[(w << 9) + (i << 6) + l] =
                __builtin_bit_cast(uint16_t, (_Float16)acc[i]);
        __syncthreads();   // the only barrier per step

        // ---- redundant per-pair reduce: rows 2(kp+s5), +1 ----
        const uint32_t* pr = ptH + (t & 1) * 2048 + kp + s5;
        float s0 = xp2.x, s1 = xp2.y;
#pragma unroll
        for (int c = 0; c < 8; ++c) {
            const v2h v = __builtin_bit_cast(v2h, pr[c * 256]);
            s0 += (float)v.x;
            s1 += (float)v.y;
        }
        // tanh (fp32): tanh(x) = sign(x) * (1-e^{-2|x|}) / (1+e^{-2|x|})
        const float u0 = __expf(-2.f * fabsf(s0));
        const float u1 = __expf(-2.f * fabsf(s1));
        float th0 = (1.f - u0) * __builtin_amdgcn_rcpf(1.f + u0);
        float th1 = (1.f - u1) * __builtin_amdgcn_rcpf(1.f + u1);
        th0 = copysignf(th0, s0);
        th1 = copysignf(th1, s1);

        if (l < 32)
            *(float2*)(outg + (size_t)t * Hsz + colbase) = make_float2(th0, th1);

        const v2h hv = { (_Float16)th0, (_Float16)th1 };
        hp  = __builtin_bit_cast(uint32_t, hv);
        xp2 = xpn;
        // no second barrier: next step writes the OTHER parity buffer, and
        // this wave can't pass the next barrier until all waves finished
        // their reduce reads of this parity.
    }
}

// ============================================================================
extern "C" void kernel_launch(void* const* d_in, const int* in_sizes, int n_in,
                              void* d_out, int out_size, void* d_ws, size_t ws_size,
                              hipStream_t stream)
{
    const float* x   = (const float*)d_in[0];   // (B,S,I)
    const float* Wih = (const float*)d_in[1];   // (H,I)
    const float* Whh = (const float*)d_in[2];   // (H,H)
    const float* bih = (const float*)d_in[3];   // (H)
    const float* bhh = (const float*)d_in[4];   // (H)
    float* out = (float*)d_out;                 // (B,S,H)

    uint32_t* w16u = (uint32_t*)d_ws;           // 512 KB packed f16 W_hh

    convert_w16<<<256, 256, 0, stream>>>(Whh, w16u);

    dim3 g1(Hsz / 128, (Bsz * Ssz) / 128);      // (4, 1024)
    xproj_gemm<<<g1, 256, 0, stream>>>(x, Wih, bih, bhh, out);

    // LDS: 131072 (weights) + 16384 (parity-2 f16 partials) = 147456 B
    rnn_scan_f16<<<Bsz, 512, 147456, stream>>>(w16u, out);
}